// Round 13
// baseline (146.423 us; speedup 1.0000x reference)
//
#include <hip/hip_runtime.h>
#include <hip/hip_bf16.h>
#include <cstdint>
#include <cstddef>

#define NG 32
#define NP 64
#define ND 512
#define HW 192
#define KS 32  // number of K=16 MFMA steps
#define EPSV 1e-5f

typedef _Float16 half8 __attribute__((ext_vector_type(8)));
typedef float floatx4 __attribute__((ext_vector_type(4)));
typedef float floatx16 __attribute__((ext_vector_type(16)));

// ---- unified pre-pass: src[b][d][x] f32 -> T[b][ks][rb][hi][l31][j] fp16
// (d = ks*16 + hi*8 + j, x = rb*32 + l31).  Fragment-ready AND stage-ready:
// a 32x32x16 frag is 1KB contiguous; a wave's 96-row tile slice is 3KB linear.
__global__ __launch_bounds__(256) void prep_frag(const float* __restrict__ gal,
                                                 const float* __restrict__ prob,
                                                 _Float16* __restrict__ galT4,
                                                 _Float16* __restrict__ probT4) {
  __shared__ float lds[16 * 192];
  const int z = blockIdx.x;   // 0..95: first NP probes, then NG gals
  const int ks = blockIdx.y;  // 0..31
  const float* src;
  _Float16* dst;
  if (z < NP) {
    src = prob + (size_t)z * ND * HW;
    dst = probT4 + (size_t)z * 98304;
  } else {
    src = gal + (size_t)(z - NP) * ND * HW;
    dst = galT4 + (size_t)(z - NP) * 98304;
  }
  src += (size_t)ks * 16 * HW;
  dst += (size_t)ks * 3072;
  const int t = threadIdx.x;
#pragma unroll
  for (int i = 0; i < 12; ++i) lds[i * 256 + t] = src[i * 256 + t];
  __syncthreads();
#pragma unroll
  for (int r = 0; r < 2; ++r) {
    const int h = r * 256 + t;  // h = rb*64 + hi*32 + l31, 384 slots
    if (h < 384) {
      const int rb = h >> 6, hi = (h >> 5) & 1, l31 = h & 31;
      half8 v;
#pragma unroll
      for (int j = 0; j < 8; ++j) v[j] = (_Float16)lds[(hi * 8 + j) * 192 + rb * 32 + l31];
      *(half8*)(dst + (size_t)h * 8) = v;
    }
  }
}

// ---- async 16B global -> LDS
__device__ __forceinline__ void g2l16(const void* g, void* l) {
  __builtin_amdgcn_global_load_lds(
      (const __attribute__((address_space(1))) void*)g,
      (__attribute__((address_space(3))) void*)l, 16, 0, 0);
}

// ---- main fused kernel: one WG (256 thr, 4 waves) per (g,p) pair ----
// SELF-PACED waves: each wave owns a PRIVATE triple-buffered LDS tile set
// (A 3KB + B 3KB per buffer) staged via global_load_lds from the frag-ready
// T4 layout, synchronized only by per-wave counted vmcnt -- ZERO barriers in
// the K-loop.  Prefetch depth 2 tiles (~2x(6 ds_read+9 MFMA) issue time) covers
// L2 latency; unsynchronized waves overlap LDS and MFMA pipes (R5/R9/R11 all
// plateaued at 87us because barrier-lockstep time-sliced the two pipes).
__global__ __launch_bounds__(256, 2) void qaconv_main(
    const _Float16* __restrict__ galT4, const _Float16* __restrict__ probT4,
    const float* __restrict__ bn_w, const float* __restrict__ bn_b,
    const float* __restrict__ bn_m, const float* __restrict__ bn_v,
    const float* __restrict__ fc_w, const float* __restrict__ fc_b,
    const float* __restrict__ lbn_w, const float* __restrict__ lbn_b,
    const float* __restrict__ lbn_m, const float* __restrict__ lbn_v,
    float* __restrict__ out) {
  __shared__ __align__(16) char tiles[4][3][6144];  // [wave][buf][A 3KB|B 3KB] = 72KB
  __shared__ float colp[2][HW];
  __shared__ float rowpart[2][HW];
  __shared__ float wsum[4];

  const int bid = blockIdx.x;
  const int g = bid >> 6, p = bid & 63;

  const int t = threadIdx.x;
  const int lane = t & 63, wid = t >> 6;
  const int wr = wid & 1;   // probe-row half (y block of 96)
  const int wc = wid >> 1;  // gal-col half (x block of 96)
  const int l31 = lane & 31, hi = lane >> 5;

  // per-lane staging sources (frag-ready: +lane*16B within each 1KB frag)
  const _Float16* pA = probT4 + (size_t)p * 98304 + wr * 1536 + lane * 8;
  const _Float16* pB = galT4 + (size_t)g * 98304 + wc * 1536 + lane * 8;
  char* myT = tiles[wid][0];  // wave-private LDS base (wave-uniform)

  floatx16 acc[3][3];
#pragma unroll
  for (int ii = 0; ii < 3; ++ii)
#pragma unroll
    for (int jj = 0; jj < 3; ++jj) acc[ii][jj] = (floatx16)0.f;

#define STAGE(sa_, sb_, off_)                 \
  {                                           \
    char* d_ = myT + (off_);                  \
    g2l16((sa_), d_);                         \
    g2l16((sa_) + 512, d_ + 1024);            \
    g2l16((sa_) + 1024, d_ + 2048);           \
    g2l16((sb_), d_ + 3072);                  \
    g2l16((sb_) + 512, d_ + 4096);            \
    g2l16((sb_) + 1024, d_ + 5120);           \
  }

  // prologue: stage tiles 0 and 1 into buffers 0 and 1
  STAGE(pA, pB, 0)
  STAGE(pA + 3072, pB + 3072, 6144)
  const _Float16* sA = pA + 2 * 3072;
  const _Float16* sB = pB + 2 * 3072;
  int stOff = 12288;  // buffer receiving stage(ks+2)
  int rdOff = 0;      // buffer holding tile ks

  for (int ks = 0; ks < KS; ++ks) {
    if (ks < KS - 2) {
      STAGE(sA, sB, stOff)
      sA += 3072;
      sB += 3072;
      stOff = (stOff == 12288) ? 0 : stOff + 6144;
      // outstanding after issue: stages ks,ks+1,ks+2 (<=18); wait until the
      // oldest 6 (stage ks, this wave's) are done -> <=12 remain.
      asm volatile("s_waitcnt vmcnt(12)" ::: "memory");
    } else if (ks == KS - 2) {
      asm volatile("s_waitcnt vmcnt(6)" ::: "memory");
    } else {
      asm volatile("s_waitcnt vmcnt(0)" ::: "memory");
    }
    const char* bA = myT + rdOff;
    const char* bB = bA + 3072;
    half8 af[3], bf[3];
#pragma unroll
    for (int f = 0; f < 3; ++f) {
      af[f] = *(const half8*)(bA + f * 1024 + lane * 16);
      bf[f] = *(const half8*)(bB + f * 1024 + lane * 16);
    }
    __builtin_amdgcn_s_setprio(1);
#pragma unroll
    for (int ii = 0; ii < 3; ++ii)
#pragma unroll
      for (int jj = 0; jj < 3; ++jj)
        acc[ii][jj] =
            __builtin_amdgcn_mfma_f32_32x32x16_f16(af[ii], bf[jj], acc[ii][jj], 0, 0, 0);
    __builtin_amdgcn_s_setprio(0);
    rdOff = (rdOff == 12288) ? 0 : rdOff + 6144;
  }
#undef STAGE

  // ---- epilogue: dual-axis max ----
  // C/D map: col X = wc*96 + fb*32 + l31, row Y = wr*96 + fa*32 + (e&3)+8*(e>>2)+4*hi
#pragma unroll
  for (int fb = 0; fb < 3; ++fb) {
    float v = -3.4e38f;
#pragma unroll
    for (int fa = 0; fa < 3; ++fa)
#pragma unroll
      for (int e = 0; e < 16; ++e) v = fmaxf(v, acc[fa][fb][e]);
    v = fmaxf(v, __shfl_xor(v, 32));
    if (lane < 32) colp[wr][wc * 96 + fb * 32 + lane] = v;
  }
  // rowmax: lane-local over 3 col-frags, 5-step butterfly across l31
#pragma unroll
  for (int fa = 0; fa < 3; ++fa)
#pragma unroll
    for (int e = 0; e < 16; ++e) {
      float rv = fmaxf(fmaxf(acc[fa][0][e], acc[fa][1][e]), acc[fa][2][e]);
      rv = fmaxf(rv, __shfl_xor(rv, 1));
      rv = fmaxf(rv, __shfl_xor(rv, 2));
      rv = fmaxf(rv, __shfl_xor(rv, 4));
      rv = fmaxf(rv, __shfl_xor(rv, 8));
      rv = fmaxf(rv, __shfl_xor(rv, 16));
      if (l31 == 0) {
        const int Y = wr * 96 + fa * 32 + (e & 3) + 8 * (e >> 2) + 4 * hi;
        rowpart[wc][Y] = rv;
      }
    }
  __syncthreads();

  // ---- fused BN -> fc dot -> logit BN -> sigmoid ----
  float partial = 0.f;
  if (t < HW) {
    const float rmax = fmaxf(rowpart[0][t], rowpart[1][t]);
    const float cmax = fmaxf(colp[0][t], colp[1][t]);
    const float scale = bn_w[0] / sqrtf(bn_v[0] + EPSV);
    const float bm = bn_m[0], bb = bn_b[0];
    partial = ((cmax - bm) * scale + bb) * fc_w[t] +
              ((rmax - bm) * scale + bb) * fc_w[HW + t];
  }
#pragma unroll
  for (int off = 1; off < 64; off <<= 1) partial += __shfl_xor(partial, off);
  if (lane == 0) wsum[wid] = partial;
  __syncthreads();
  if (t == 0) {
    const float sum = fc_b[0] + wsum[0] + wsum[1] + wsum[2] + wsum[3];
    const float logit = (sum - lbn_m[0]) * (lbn_w[0] / sqrtf(lbn_v[0] + EPSV)) + lbn_b[0];
    out[bid] = 1.f / (1.f + expf(-logit * 0.1f));
  }
}

// ---------------- naive f32 fallback (only if ws too small) ----------------
__global__ __launch_bounds__(256) void qaconv_naive(
    const float* __restrict__ gal, const float* __restrict__ prob,
    const float* __restrict__ bn_w, const float* __restrict__ bn_b,
    const float* __restrict__ bn_m, const float* __restrict__ bn_v,
    const float* __restrict__ fc_w, const float* __restrict__ fc_b,
    const float* __restrict__ lbn_w, const float* __restrict__ lbn_b,
    const float* __restrict__ lbn_m, const float* __restrict__ lbn_v,
    float* __restrict__ out) {
  __shared__ float prow[ND];
  __shared__ float rowmaxs[HW];
  __shared__ float colmaxs[HW];
  __shared__ float red[4];
  const int bid = blockIdx.x;
  const int g = bid >> 6, p = bid & 63;
  const int t = threadIdx.x, lane = t & 63, wid = t >> 6;
  const float* gp = gal + (size_t)g * ND * HW;
  const float* pp = prob + (size_t)p * ND * HW;
  float colmax = -3.4e38f;
  for (int y = 0; y < HW; ++y) {
    for (int k = t; k < ND; k += 256) prow[k] = pp[(size_t)k * HW + y];
    __syncthreads();
    float sv = -3.4e38f;
    if (t < HW) {
      sv = 0.f;
      for (int k = 0; k < ND; ++k) sv = fmaf(prow[k], gp[(size_t)k * HW + t], sv);
      colmax = fmaxf(colmax, sv);
    }
    float m = sv;
#pragma unroll
    for (int off = 1; off < 64; off <<= 1) m = fmaxf(m, __shfl_xor(m, off));
    if (lane == 0) red[wid] = m;
    __syncthreads();
    if (t == 0) rowmaxs[y] = fmaxf(fmaxf(red[0], red[1]), fmaxf(red[2], red[3]));
    __syncthreads();
  }
  if (t < HW) colmaxs[t] = colmax;
  __syncthreads();
  float partial = 0.f;
  for (int j = t; j < 2 * HW; j += 256) {
    const float v = (j < HW) ? colmaxs[j] : rowmaxs[j - HW];
    const float sc = (v - bn_m[0]) * (bn_w[0] / sqrtf(bn_v[0] + EPSV)) + bn_b[0];
    partial += sc * fc_w[j];
  }
#pragma unroll
  for (int off = 1; off < 64; off <<= 1) partial += __shfl_xor(partial, off);
  if (lane == 0) red[wid] = partial;
  __syncthreads();
  if (t == 0) {
    const float sum = fc_b[0] + red[0] + red[1] + red[2] + red[3];
    const float logit = (sum - lbn_m[0]) * (lbn_w[0] / sqrtf(lbn_v[0] + EPSV)) + lbn_b[0];
    out[bid] = 1.f / (1.f + expf(-logit * 0.1f));
  }
}

extern "C" void kernel_launch(void* const* d_in, const int* in_sizes, int n_in,
                              void* d_out, int out_size, void* d_ws, size_t ws_size,
                              hipStream_t stream) {
  const float* gal = (const float*)d_in[0];
  const float* prob = (const float*)d_in[1];
  const float* bn_w = (const float*)d_in[2];
  const float* bn_b = (const float*)d_in[3];
  const float* bn_m = (const float*)d_in[4];
  const float* bn_v = (const float*)d_in[5];
  const float* fc_w = (const float*)d_in[6];
  const float* fc_b = (const float*)d_in[7];
  const float* lbn_w = (const float*)d_in[8];
  const float* lbn_b = (const float*)d_in[9];
  const float* lbn_m = (const float*)d_in[10];
  const float* lbn_v = (const float*)d_in[11];
  float* out = (float*)d_out;

  const size_t probT4_elems = (size_t)NP * 98304;  // 6.29M halves
  const size_t galT4_elems = (size_t)NG * 98304;   // 3.15M halves
  const size_t ws_needed = (probT4_elems + galT4_elems) * sizeof(_Float16);
  if (ws_size >= ws_needed) {
    _Float16* probT4 = (_Float16*)d_ws;
    _Float16* galT4 = probT4 + probT4_elems;
    prep_frag<<<dim3(NP + NG, KS), dim3(256), 0, stream>>>(gal, prob, galT4, probT4);
    qaconv_main<<<dim3(NG * NP), dim3(256), 0, stream>>>(
        galT4, probT4, bn_w, bn_b, bn_m, bn_v, fc_w, fc_b, lbn_w, lbn_b, lbn_m, lbn_v, out);
  } else {
    qaconv_naive<<<dim3(NG * NP), dim3(256), 0, stream>>>(
        gal, prob, bn_w, bn_b, bn_m, bn_v, fc_w, fc_b, lbn_w, lbn_b, lbn_m, lbn_v, out);
  }
}

// Round 14
// 132.486 us; speedup vs baseline: 1.1052x; 1.1052x over previous
//
#include <hip/hip_runtime.h>
#include <hip/hip_bf16.h>
#include <cstdint>
#include <cstddef>

#define NG 32
#define NP 64
#define ND 512
#define HW 192
#define KS 32  // number of K=16 MFMA steps
#define EPSV 1e-5f

typedef _Float16 half8 __attribute__((ext_vector_type(8)));
typedef float floatx4 __attribute__((ext_vector_type(4)));
typedef float floatx16 __attribute__((ext_vector_type(16)));

// ---- unified pre-pass: src[b][d][x] f32 -> T[b][ks][rb][hi][l31][j] fp16
// (d = ks*16 + hi*8 + j, x = rb*32 + l31).  Fragment-ready AND stage-ready:
// a 32x32x16 frag is 1KB contiguous; per-ks slice is 6KB linear.
__global__ __launch_bounds__(256) void prep_frag(const float* __restrict__ gal,
                                                 const float* __restrict__ prob,
                                                 _Float16* __restrict__ galT4,
                                                 _Float16* __restrict__ probT4) {
  __shared__ float lds[16 * 192];
  const int z = blockIdx.x;   // 0..95: first NP probes, then NG gals
  const int ks = blockIdx.y;  // 0..31
  const float* src;
  _Float16* dst;
  if (z < NP) {
    src = prob + (size_t)z * ND * HW;
    dst = probT4 + (size_t)z * 98304;
  } else {
    src = gal + (size_t)(z - NP) * ND * HW;
    dst = galT4 + (size_t)(z - NP) * 98304;
  }
  src += (size_t)ks * 16 * HW;
  dst += (size_t)ks * 3072;
  const int t = threadIdx.x;
#pragma unroll
  for (int i = 0; i < 12; ++i) lds[i * 256 + t] = src[i * 256 + t];
  __syncthreads();
#pragma unroll
  for (int r = 0; r < 2; ++r) {
    const int h = r * 256 + t;  // h = rb*64 + hi*32 + l31, 384 slots
    if (h < 384) {
      const int rb = h >> 6, hi = (h >> 5) & 1, l31 = h & 31;
      half8 v;
#pragma unroll
      for (int j = 0; j < 8; ++j) v[j] = (_Float16)lds[(hi * 8 + j) * 192 + rb * 32 + l31];
      *(half8*)(dst + (size_t)h * 8) = v;
    }
  }
}

// ---- async 16B global -> LDS
__device__ __forceinline__ void g2l16(const void* g, void* l) {
  __builtin_amdgcn_global_load_lds(
      (const __attribute__((address_space(1))) void*)g,
      (__attribute__((address_space(3))) void*)l, 16, 0, 0);
}

// ---- main fused kernel: one WG (256 thr, 4 waves) per (g,p) pair ----
// T3/T4 counted-vmcnt schedule: BK=16, FOUR shared LDS buffers (48KB), one raw
// s_barrier per K-step preceded by s_waitcnt vmcnt(6).  stage(kt+2) is issued
// 2 steps (~1200 cyc) ahead and stays IN FLIGHT across barriers -- the K-loop
// contains no other VMEM, so the in-order vmcnt count is exact (R7's counted
// vmcnt failed because A-frag global loads polluted the queue).  Buffer
// liveness mod 4: window kt reads buf[kt&3], writes buf[(kt+2)&3]/[(kt+3)&3].
__global__ __launch_bounds__(256, 2) void qaconv_main(
    const _Float16* __restrict__ galT4, const _Float16* __restrict__ probT4,
    const float* __restrict__ bn_w, const float* __restrict__ bn_b,
    const float* __restrict__ bn_m, const float* __restrict__ bn_v,
    const float* __restrict__ fc_w, const float* __restrict__ fc_b,
    const float* __restrict__ lbn_w, const float* __restrict__ lbn_b,
    const float* __restrict__ lbn_m, const float* __restrict__ lbn_v,
    float* __restrict__ out) {
  __shared__ __align__(16) char tiles[4][12288];  // [buf][A 6KB | B 6KB] = 48KB
  __shared__ float colp[2][HW];
  __shared__ float rowpart[2][HW];
  __shared__ float wsum[4];

  const int bid = blockIdx.x;
  const int g = bid >> 6, p = bid & 63;

  const int t = threadIdx.x;
  const int lane = t & 63, wid = t >> 6;
  const int wr = wid & 1;   // probe-row half (y block of 96)
  const int wc = wid >> 1;  // gal-col half (x block of 96)
  const int l31 = lane & 31, hi = lane >> 5;

  // staging roles: wid 0/1 stage A halves, wid 2/3 stage B halves (3KB each,
  // 3 x g2l16 of 1KB).  Source is the frag-ready T4 slice (linear).
  const _Float16* srcA = probT4 + (size_t)p * 98304 + (wid & 1) * 1536 + lane * 8;
  const _Float16* srcB = galT4 + (size_t)g * 98304 + (wid & 1) * 1536 + lane * 8;
  const _Float16* mySrc = (wid < 2) ? srcA : srcB;
  const int myDst = (wid >> 1) * 6144 + (wid & 1) * 3072;  // wave-uniform

  floatx16 acc[3][3];
#pragma unroll
  for (int ii = 0; ii < 3; ++ii)
#pragma unroll
    for (int jj = 0; jj < 3; ++jj) acc[ii][jj] = (floatx16)0.f;

#define STAGE(ks_, buf_)                                        \
  {                                                             \
    char* d_ = tiles[buf_] + myDst;                             \
    const _Float16* s_ = mySrc + (size_t)(ks_)*3072;            \
    g2l16(s_, d_);                                              \
    g2l16(s_ + 512, d_ + 1024);                                 \
    g2l16(s_ + 1024, d_ + 2048);                                \
  }

#define COMPUTE(buf_)                                                            \
  {                                                                              \
    const char* bA = tiles[buf_];                                                \
    const char* bB = bA + 6144;                                                  \
    half8 af[3], bf[3];                                                          \
    _Pragma("unroll") for (int f = 0; f < 3; ++f) {                              \
      af[f] = *(const half8*)(bA + (wr * 3 + f) * 1024 + lane * 16);             \
      bf[f] = *(const half8*)(bB + (wc * 3 + f) * 1024 + lane * 16);             \
    }                                                                            \
    __builtin_amdgcn_s_setprio(1);                                               \
    _Pragma("unroll") for (int ii = 0; ii < 3; ++ii)                             \
        _Pragma("unroll") for (int jj = 0; jj < 3; ++jj)                         \
            acc[ii][jj] = __builtin_amdgcn_mfma_f32_32x32x16_f16(af[ii], bf[jj], \
                                                                 acc[ii][jj], 0, 0, 0); \
    __builtin_amdgcn_s_setprio(0);                                               \
  }

  // prologue: stage tiles 0,1 (6 loads outstanding)
  STAGE(0, 0)
  STAGE(1, 1)

#pragma unroll 2
  for (int kt = 0; kt < KS - 2; ++kt) {
    STAGE(kt + 2, (kt + 2) & 3)
    // drain own stage(kt) (oldest), keep stage(kt+1)+stage(kt+2)=6 in flight
    asm volatile("s_waitcnt vmcnt(6)" ::: "memory");
    __builtin_amdgcn_s_barrier();  // all waves' stage(kt) done; no vmem drain
    COMPUTE(kt & 3)
  }
  asm volatile("s_waitcnt vmcnt(3)" ::: "memory");
  __builtin_amdgcn_s_barrier();
  COMPUTE((KS - 2) & 3)
  asm volatile("s_waitcnt vmcnt(0)" ::: "memory");
  __builtin_amdgcn_s_barrier();
  COMPUTE((KS - 1) & 3)
#undef STAGE
#undef COMPUTE

  // ---- epilogue: dual-axis max ----
  // C/D map: col X = wc*96 + fb*32 + l31, row Y = wr*96 + fa*32 + (e&3)+8*(e>>2)+4*hi
#pragma unroll
  for (int fb = 0; fb < 3; ++fb) {
    float v = -3.4e38f;
#pragma unroll
    for (int fa = 0; fa < 3; ++fa)
#pragma unroll
      for (int e = 0; e < 16; ++e) v = fmaxf(v, acc[fa][fb][e]);
    v = fmaxf(v, __shfl_xor(v, 32));
    if (lane < 32) colp[wr][wc * 96 + fb * 32 + lane] = v;
  }
  // rowmax: lane-local over 3 col-frags, 5-step butterfly across l31
#pragma unroll
  for (int fa = 0; fa < 3; ++fa)
#pragma unroll
    for (int e = 0; e < 16; ++e) {
      float rv = fmaxf(fmaxf(acc[fa][0][e], acc[fa][1][e]), acc[fa][2][e]);
      rv = fmaxf(rv, __shfl_xor(rv, 1));
      rv = fmaxf(rv, __shfl_xor(rv, 2));
      rv = fmaxf(rv, __shfl_xor(rv, 4));
      rv = fmaxf(rv, __shfl_xor(rv, 8));
      rv = fmaxf(rv, __shfl_xor(rv, 16));
      if (l31 == 0) {
        const int Y = wr * 96 + fa * 32 + (e & 3) + 8 * (e >> 2) + 4 * hi;
        rowpart[wc][Y] = rv;
      }
    }
  __syncthreads();

  // ---- fused BN -> fc dot -> logit BN -> sigmoid ----
  float partial = 0.f;
  if (t < HW) {
    const float rmax = fmaxf(rowpart[0][t], rowpart[1][t]);
    const float cmax = fmaxf(colp[0][t], colp[1][t]);
    const float scale = bn_w[0] / sqrtf(bn_v[0] + EPSV);
    const float bm = bn_m[0], bb = bn_b[0];
    partial = ((cmax - bm) * scale + bb) * fc_w[t] +
              ((rmax - bm) * scale + bb) * fc_w[HW + t];
  }
#pragma unroll
  for (int off = 1; off < 64; off <<= 1) partial += __shfl_xor(partial, off);
  if (lane == 0) wsum[wid] = partial;
  __syncthreads();
  if (t == 0) {
    const float sum = fc_b[0] + wsum[0] + wsum[1] + wsum[2] + wsum[3];
    const float logit = (sum - lbn_m[0]) * (lbn_w[0] / sqrtf(lbn_v[0] + EPSV)) + lbn_b[0];
    out[bid] = 1.f / (1.f + expf(-logit * 0.1f));
  }
}

// ---------------- naive f32 fallback (only if ws too small) ----------------
__global__ __launch_bounds__(256) void qaconv_naive(
    const float* __restrict__ gal, const float* __restrict__ prob,
    const float* __restrict__ bn_w, const float* __restrict__ bn_b,
    const float* __restrict__ bn_m, const float* __restrict__ bn_v,
    const float* __restrict__ fc_w, const float* __restrict__ fc_b,
    const float* __restrict__ lbn_w, const float* __restrict__ lbn_b,
    const float* __restrict__ lbn_m, const float* __restrict__ lbn_v,
    float* __restrict__ out) {
  __shared__ float prow[ND];
  __shared__ float rowmaxs[HW];
  __shared__ float colmaxs[HW];
  __shared__ float red[4];
  const int bid = blockIdx.x;
  const int g = bid >> 6, p = bid & 63;
  const int t = threadIdx.x, lane = t & 63, wid = t >> 6;
  const float* gp = gal + (size_t)g * ND * HW;
  const float* pp = prob + (size_t)p * ND * HW;
  float colmax = -3.4e38f;
  for (int y = 0; y < HW; ++y) {
    for (int k = t; k < ND; k += 256) prow[k] = pp[(size_t)k * HW + y];
    __syncthreads();
    float sv = -3.4e38f;
    if (t < HW) {
      sv = 0.f;
      for (int k = 0; k < ND; ++k) sv = fmaf(prow[k], gp[(size_t)k * HW + t], sv);
      colmax = fmaxf(colmax, sv);
    }
    float m = sv;
#pragma unroll
    for (int off = 1; off < 64; off <<= 1) m = fmaxf(m, __shfl_xor(m, off));
    if (lane == 0) red[wid] = m;
    __syncthreads();
    if (t == 0) rowmaxs[y] = fmaxf(fmaxf(red[0], red[1]), fmaxf(red[2], red[3]));
    __syncthreads();
  }
  if (t < HW) colmaxs[t] = colmax;
  __syncthreads();
  float partial = 0.f;
  for (int j = t; j < 2 * HW; j += 256) {
    const float v = (j < HW) ? colmaxs[j] : rowmaxs[j - HW];
    const float sc = (v - bn_m[0]) * (bn_w[0] / sqrtf(bn_v[0] + EPSV)) + bn_b[0];
    partial += sc * fc_w[j];
  }
#pragma unroll
  for (int off = 1; off < 64; off <<= 1) partial += __shfl_xor(partial, off);
  if (lane == 0) red[wid] = partial;
  __syncthreads();
  if (t == 0) {
    const float sum = fc_b[0] + red[0] + red[1] + red[2] + red[3];
    const float logit = (sum - lbn_m[0]) * (lbn_w[0] / sqrtf(lbn_v[0] + EPSV)) + lbn_b[0];
    out[bid] = 1.f / (1.f + expf(-logit * 0.1f));
  }
}

extern "C" void kernel_launch(void* const* d_in, const int* in_sizes, int n_in,
                              void* d_out, int out_size, void* d_ws, size_t ws_size,
                              hipStream_t stream) {
  const float* gal = (const float*)d_in[0];
  const float* prob = (const float*)d_in[1];
  const float* bn_w = (const float*)d_in[2];
  const float* bn_b = (const float*)d_in[3];
  const float* bn_m = (const float*)d_in[4];
  const float* bn_v = (const float*)d_in[5];
  const float* fc_w = (const float*)d_in[6];
  const float* fc_b = (const float*)d_in[7];
  const float* lbn_w = (const float*)d_in[8];
  const float* lbn_b = (const float*)d_in[9];
  const float* lbn_m = (const float*)d_in[10];
  const float* lbn_v = (const float*)d_in[11];
  float* out = (float*)d_out;

  const size_t probT4_elems = (size_t)NP * 98304;  // 6.29M halves
  const size_t galT4_elems = (size_t)NG * 98304;   // 3.15M halves
  const size_t ws_needed = (probT4_elems + galT4_elems) * sizeof(_Float16);
  if (ws_size >= ws_needed) {
    _Float16* probT4 = (_Float16*)d_ws;
    _Float16* galT4 = probT4 + probT4_elems;
    prep_frag<<<dim3(NP + NG, KS), dim3(256), 0, stream>>>(gal, prob, galT4, probT4);
    qaconv_main<<<dim3(NG * NP), dim3(256), 0, stream>>>(
        galT4, probT4, bn_w, bn_b, bn_m, bn_v, fc_w, fc_b, lbn_w, lbn_b, lbn_m, lbn_v, out);
  } else {
    qaconv_naive<<<dim3(NG * NP), dim3(256), 0, stream>>>(
        gal, prob, bn_w, bn_b, bn_m, bn_v, fc_w, fc_b, lbn_w, lbn_b, lbn_m, lbn_v, out);
  }
}

// Round 15
// 97.187 us; speedup vs baseline: 1.5066x; 1.3632x over previous
//
#include <hip/hip_runtime.h>
#include <hip/hip_bf16.h>
#include <cstdint>
#include <cstddef>

#define NG 32
#define NP 64
#define ND 512
#define HW 192
#define KS 32  // number of K=16 slices in pre-tiled layout
#define EPSV 1e-5f

typedef _Float16 half8 __attribute__((ext_vector_type(8)));
typedef float floatx4 __attribute__((ext_vector_type(4)));
typedef float floatx16 __attribute__((ext_vector_type(16)));

// ---- unified pre-pass: src[b][d][x] f32 -> T[b][ks][rb][hi][l31][j] fp16
// (d = ks*16 + hi*8 + j, x = rb*32 + l31).  Fragment-ready AND stage-ready:
// a 32x32x16 frag is 1KB contiguous; a BK=32 tile (2 ks slices) is 12KB linear.
__global__ __launch_bounds__(256) void prep_frag(const float* __restrict__ gal,
                                                 const float* __restrict__ prob,
                                                 _Float16* __restrict__ galT4,
                                                 _Float16* __restrict__ probT4) {
  __shared__ float lds[16 * 192];
  const int z = blockIdx.x;   // 0..95: first NP probes, then NG gals
  const int ks = blockIdx.y;  // 0..31
  const float* src;
  _Float16* dst;
  if (z < NP) {
    src = prob + (size_t)z * ND * HW;
    dst = probT4 + (size_t)z * 98304;
  } else {
    src = gal + (size_t)(z - NP) * ND * HW;
    dst = galT4 + (size_t)(z - NP) * 98304;
  }
  src += (size_t)ks * 16 * HW;
  dst += (size_t)ks * 3072;
  const int t = threadIdx.x;
#pragma unroll
  for (int i = 0; i < 12; ++i) lds[i * 256 + t] = src[i * 256 + t];
  __syncthreads();
#pragma unroll
  for (int r = 0; r < 2; ++r) {
    const int h = r * 256 + t;  // h = rb*64 + hi*32 + l31, 384 slots
    if (h < 384) {
      const int rb = h >> 6, hi = (h >> 5) & 1, l31 = h & 31;
      half8 v;
#pragma unroll
      for (int j = 0; j < 8; ++j) v[j] = (_Float16)lds[(hi * 8 + j) * 192 + rb * 32 + l31];
      *(half8*)(dst + (size_t)h * 8) = v;
    }
  }
}

// ---- async 16B global -> LDS
__device__ __forceinline__ void g2l16(const void* g, void* l) {
  __builtin_amdgcn_global_load_lds(
      (const __attribute__((address_space(1))) void*)g,
      (__attribute__((address_space(3))) void*)l, 16, 0, 0);
}

// ---- main fused kernel: one WG (256 thr, 4 waves) per (g,p) pair ----
// R11 structure (BK=32, A+B in LDS, 18 MFMA / barrier, 16 barriers) with ONE
// change-set: TRIPLE buffer + raw s_barrier + counted vmcnt(6), stage lead 2
// K-tiles.  The K-loop VMEM queue holds ONLY stage loads, so vmcnt(6) ==
// "my stage(kt) done; stage(kt+1)/(kt+2) stay in flight across the barrier"
// -- removes the vmcnt(0) drain hipcc emits at __syncthreads (the R11 stall).
// Slot order [wait; barrier; STAGE(kt+2); COMPUTE(kt)]: barrier(kt) guarantees
// compute(kt-1) done block-wide before STAGE(kt+2) overwrites buf[(kt-1)%3].
__global__ __launch_bounds__(256, 2) void qaconv_main(
    const _Float16* __restrict__ galT4, const _Float16* __restrict__ probT4,
    const float* __restrict__ bn_w, const float* __restrict__ bn_b,
    const float* __restrict__ bn_m, const float* __restrict__ bn_v,
    const float* __restrict__ fc_w, const float* __restrict__ fc_b,
    const float* __restrict__ lbn_w, const float* __restrict__ lbn_b,
    const float* __restrict__ lbn_m, const float* __restrict__ lbn_v,
    float* __restrict__ out) {
  // K-loop: 3 buffers x [A 12KB | B 12KB] = 73728 B; epilogue overlays
  // rowbuf[192][66] f32 (50688 B) on the same storage.
  __shared__ __align__(16) char shmem[73728];
  __shared__ float colp[2][HW];
  __shared__ float wsum[4];
  float(*rowbuf)[66] = (float(*)[66])shmem;

  const int bid = blockIdx.x;
  const int g = bid >> 6, p = bid & 63;

  const int t = threadIdx.x;
  const int lane = t & 63, wid = t >> 6;
  const int wr = wid & 1;   // probe-row half (y block of 96)
  const int wc = wid >> 1;  // gal-col half (x block of 96)
  const int l31 = lane & 31, hi = lane >> 5;

  // staging sources (per-lane): one BK=32 tile = 6144 halves (12KB) linear;
  // wave w copies 3 chunks of 1KB at src w*1KB + r*4KB -> LDS same offsets.
  const _Float16* pAl = probT4 + (size_t)p * 98304 + wid * 512 + lane * 8;
  const _Float16* pBl = galT4 + (size_t)g * 98304 + wid * 512 + lane * 8;
  const int sdst = wid * 1024;  // wave-uniform LDS dest base (+ lane*16 by HW)

  char* const b0 = shmem;
  char* const b1 = shmem + 24576;
  char* const b2 = shmem + 49152;

  floatx16 acc[3][3];
#pragma unroll
  for (int ii = 0; ii < 3; ++ii)
#pragma unroll
    for (int jj = 0; jj < 3; ++jj) acc[ii][jj] = (floatx16)0.f;

#define STAGE(kt_, base_)                                            \
  {                                                                  \
    char* db_ = (base_) + sdst;                                      \
    const _Float16* sa_ = pAl + (size_t)(kt_)*6144;                  \
    const _Float16* sb_ = pBl + (size_t)(kt_)*6144;                  \
    g2l16(sa_, db_);                                                 \
    g2l16(sa_ + 2048, db_ + 4096);                                   \
    g2l16(sa_ + 4096, db_ + 8192);                                   \
    g2l16(sb_, db_ + 12288);                                         \
    g2l16(sb_ + 2048, db_ + 16384);                                  \
    g2l16(sb_ + 4096, db_ + 20480);                                  \
  }

#define KC_BODY(base_, kc_)                                                      \
  {                                                                              \
    const char* bA_ = (base_) + (kc_)*6144;                                      \
    const char* bB_ = (base_) + 12288 + (kc_)*6144;                              \
    half8 af[3], bf[3];                                                          \
    _Pragma("unroll") for (int f = 0; f < 3; ++f) {                              \
      af[f] = *(const half8*)(bA_ + (wr * 3 + f) * 1024 + lane * 16);            \
      bf[f] = *(const half8*)(bB_ + (wc * 3 + f) * 1024 + lane * 16);            \
    }                                                                            \
    __builtin_amdgcn_s_setprio(1);                                               \
    _Pragma("unroll") for (int ii = 0; ii < 3; ++ii)                             \
        _Pragma("unroll") for (int jj = 0; jj < 3; ++jj)                         \
            acc[ii][jj] = __builtin_amdgcn_mfma_f32_32x32x16_f16(af[ii], bf[jj], \
                                                                 acc[ii][jj], 0, 0, 0); \
    __builtin_amdgcn_s_setprio(0);                                               \
  }

#define COMPUTE(base_) KC_BODY(base_, 0) KC_BODY(base_, 1)

#define SLOT(kt_, rdb_, stb_, doStage_)                  \
  {                                                      \
    asm volatile("s_waitcnt vmcnt(6)" ::: "memory");     \
    __builtin_amdgcn_s_barrier();                        \
    if (doStage_) STAGE((kt_) + 2, stb_)                 \
    COMPUTE(rdb_)                                        \
  }

  // prologue: stage tiles 0,1 (12 loads/wave outstanding)
  STAGE(0, b0)
  STAGE(1, b1)

#pragma unroll 1
  for (int m = 0; m < 5; ++m) {
    const int kt = m * 3;
    SLOT(kt + 0, b0, b2, true)
    SLOT(kt + 1, b1, b0, true)
    SLOT(kt + 2, b2, b1, (m < 4))  // kt=14: stage(16) doesn't exist
  }
  // kt = 15: only stage(15) (6 loads) outstanding
  asm volatile("s_waitcnt vmcnt(0)" ::: "memory");
  __builtin_amdgcn_s_barrier();
  COMPUTE(b0)
#undef STAGE
#undef KC_BODY
#undef COMPUTE
#undef SLOT

  // ---- epilogue: dual-axis max ----
  // C/D map: col X = wc*96 + fb*32 + l31, row Y = wr*96 + fa*32 + (e&3)+8*(e>>2)+4*hi
#pragma unroll
  for (int fb = 0; fb < 3; ++fb) {
    float v = -3.4e38f;
#pragma unroll
    for (int fa = 0; fa < 3; ++fa)
#pragma unroll
      for (int e = 0; e < 16; ++e) v = fmaxf(v, acc[fa][fb][e]);
    v = fmaxf(v, __shfl_xor(v, 32));
    if (lane < 32) colp[wr][wc * 96 + fb * 32 + lane] = v;
  }
  __syncthreads();  // all waves done reading LDS tiles -> safe to overlay rowbuf
  // rowmax partials -> rowbuf (overlays tile storage)
#pragma unroll
  for (int fa = 0; fa < 3; ++fa)
#pragma unroll
    for (int e = 0; e < 16; ++e) {
      float rv = acc[fa][0][e];
      rv = fmaxf(rv, acc[fa][1][e]);
      rv = fmaxf(rv, acc[fa][2][e]);
      const int Y = wr * 96 + fa * 32 + (e & 3) + 8 * (e >> 2) + 4 * hi;
      rowbuf[Y][wc * 32 + l31] = rv;
    }
  __syncthreads();

  // ---- fused BN -> fc dot -> logit BN -> sigmoid ----
  float partial = 0.f;
  if (t < HW) {
    const float* rb = rowbuf[t];
    float rmax = -3.4e38f;
#pragma unroll
    for (int j = 0; j < 16; ++j) {
      const floatx4 v = *(const floatx4*)&rb[j * 4];
      rmax = fmaxf(rmax, fmaxf(fmaxf(v[0], v[1]), fmaxf(v[2], v[3])));
    }
    const float cmax = fmaxf(colp[0][t], colp[1][t]);
    const float scale = bn_w[0] / sqrtf(bn_v[0] + EPSV);
    const float bm = bn_m[0], bb = bn_b[0];
    partial = ((cmax - bm) * scale + bb) * fc_w[t] +
              ((rmax - bm) * scale + bb) * fc_w[HW + t];
  }
#pragma unroll
  for (int off = 1; off < 64; off <<= 1) partial += __shfl_xor(partial, off);
  if (lane == 0) wsum[wid] = partial;
  __syncthreads();
  if (t == 0) {
    const float sum = fc_b[0] + wsum[0] + wsum[1] + wsum[2] + wsum[3];
    const float logit = (sum - lbn_m[0]) * (lbn_w[0] / sqrtf(lbn_v[0] + EPSV)) + lbn_b[0];
    out[bid] = 1.f / (1.f + expf(-logit * 0.1f));
  }
}

// ---------------- naive f32 fallback (only if ws too small) ----------------
__global__ __launch_bounds__(256) void qaconv_naive(
    const float* __restrict__ gal, const float* __restrict__ prob,
    const float* __restrict__ bn_w, const float* __restrict__ bn_b,
    const float* __restrict__ bn_m, const float* __restrict__ bn_v,
    const float* __restrict__ fc_w, const float* __restrict__ fc_b,
    const float* __restrict__ lbn_w, const float* __restrict__ lbn_b,
    const float* __restrict__ lbn_m, const float* __restrict__ lbn_v,
    float* __restrict__ out) {
  __shared__ float prow[ND];
  __shared__ float rowmaxs[HW];
  __shared__ float colmaxs[HW];
  __shared__ float red[4];
  const int bid = blockIdx.x;
  const int g = bid >> 6, p = bid & 63;
  const int t = threadIdx.x, lane = t & 63, wid = t >> 6;
  const float* gp = gal + (size_t)g * ND * HW;
  const float* pp = prob + (size_t)p * ND * HW;
  float colmax = -3.4e38f;
  for (int y = 0; y < HW; ++y) {
    for (int k = t; k < ND; k += 256) prow[k] = pp[(size_t)k * HW + y];
    __syncthreads();
    float sv = -3.4e38f;
    if (t < HW) {
      sv = 0.f;
      for (int k = 0; k < ND; ++k) sv = fmaf(prow[k], gp[(size_t)k * HW + t], sv);
      colmax = fmaxf(colmax, sv);
    }
    float m = sv;
#pragma unroll
    for (int off = 1; off < 64; off <<= 1) m = fmaxf(m, __shfl_xor(m, off));
    if (lane == 0) red[wid] = m;
    __syncthreads();
    if (t == 0) rowmaxs[y] = fmaxf(fmaxf(red[0], red[1]), fmaxf(red[2], red[3]));
    __syncthreads();
  }
  if (t < HW) colmaxs[t] = colmax;
  __syncthreads();
  float partial = 0.f;
  for (int j = t; j < 2 * HW; j += 256) {
    const float v = (j < HW) ? colmaxs[j] : rowmaxs[j - HW];
    const float sc = (v - bn_m[0]) * (bn_w[0] / sqrtf(bn_v[0] + EPSV)) + bn_b[0];
    partial += sc * fc_w[j];
  }
#pragma unroll
  for (int off = 1; off < 64; off <<= 1) partial += __shfl_xor(partial, off);
  if (lane == 0) red[wid] = partial;
  __syncthreads();
  if (t == 0) {
    const float sum = fc_b[0] + red[0] + red[1] + red[2] + red[3];
    const float logit = (sum - lbn_m[0]) * (lbn_w[0] / sqrtf(lbn_v[0] + EPSV)) + lbn_b[0];
    out[bid] = 1.f / (1.f + expf(-logit * 0.1f));
  }
}

extern "C" void kernel_launch(void* const* d_in, const int* in_sizes, int n_in,
                              void* d_out, int out_size, void* d_ws, size_t ws_size,
                              hipStream_t stream) {
  const float* gal = (const float*)d_in[0];
  const float* prob = (const float*)d_in[1];
  const float* bn_w = (const float*)d_in[2];
  const float* bn_b = (const float*)d_in[3];
  const float* bn_m = (const float*)d_in[4];
  const float* bn_v = (const float*)d_in[5];
  const float* fc_w = (const float*)d_in[6];
  const float* fc_b = (const float*)d_in[7];
  const float* lbn_w = (const float*)d_in[8];
  const float* lbn_b = (const float*)d_in[9];
  const float* lbn_m = (const float*)d_in[10];
  const float* lbn_v = (const float*)d_in[11];
  float* out = (float*)d_out;

  const size_t probT4_elems = (size_t)NP * 98304;  // 6.29M halves
  const size_t galT4_elems = (size_t)NG * 98304;   // 3.15M halves
  const size_t ws_needed = (probT4_elems + galT4_elems) * sizeof(_Float16);
  if (ws_size >= ws_needed) {
    _Float16* probT4 = (_Float16*)d_ws;
    _Float16* galT4 = probT4 + probT4_elems;
    prep_frag<<<dim3(NP + NG, KS), dim3(256), 0, stream>>>(gal, prob, galT4, probT4);
    qaconv_main<<<dim3(NG * NP), dim3(256), 0, stream>>>(
        galT4, probT4, bn_w, bn_b, bn_m, bn_v, fc_w, fc_b, lbn_w, lbn_b, lbn_m, lbn_v, out);
  } else {
    qaconv_naive<<<dim3(NG * NP), dim3(256), 0, stream>>>(
        gal, prob, bn_w, bn_b, bn_m, bn_v, fc_w, fc_b, lbn_w, lbn_b, lbn_m, lbn_v, out);
  }
}

// Round 16
// 90.030 us; speedup vs baseline: 1.6264x; 1.0795x over previous
//
#include <hip/hip_runtime.h>
#include <hip/hip_bf16.h>
#include <cstdint>
#include <cstddef>

#define NG 32
#define NP 64
#define ND 512
#define HW 192
#define KS 32  // number of K=16 slices in pre-tiled layout
#define EPSV 1e-5f

typedef _Float16 half8 __attribute__((ext_vector_type(8)));
typedef float floatx4 __attribute__((ext_vector_type(4)));
typedef float floatx16 __attribute__((ext_vector_type(16)));

// ---- unified pre-pass: src[b][d][x] f32 -> T[b][ks][rb][hi][l31][j] fp16
// (d = ks*16 + hi*8 + j, x = rb*32 + l31).  Fragment-ready AND stage-ready.
__global__ __launch_bounds__(256) void prep_frag(const float* __restrict__ gal,
                                                 const float* __restrict__ prob,
                                                 _Float16* __restrict__ galT4,
                                                 _Float16* __restrict__ probT4) {
  __shared__ float lds[16 * 192];
  const int z = blockIdx.x;   // 0..95: first NP probes, then NG gals
  const int ks = blockIdx.y;  // 0..31
  const float* src;
  _Float16* dst;
  if (z < NP) {
    src = prob + (size_t)z * ND * HW;
    dst = probT4 + (size_t)z * 98304;
  } else {
    src = gal + (size_t)(z - NP) * ND * HW;
    dst = galT4 + (size_t)(z - NP) * 98304;
  }
  src += (size_t)ks * 16 * HW;
  dst += (size_t)ks * 3072;
  const int t = threadIdx.x;
#pragma unroll
  for (int i = 0; i < 12; ++i) lds[i * 256 + t] = src[i * 256 + t];
  __syncthreads();
#pragma unroll
  for (int r = 0; r < 2; ++r) {
    const int h = r * 256 + t;  // h = rb*64 + hi*32 + l31, 384 slots
    if (h < 384) {
      const int rb = h >> 6, hi = (h >> 5) & 1, l31 = h & 31;
      half8 v;
#pragma unroll
      for (int j = 0; j < 8; ++j) v[j] = (_Float16)lds[(hi * 8 + j) * 192 + rb * 32 + l31];
      *(half8*)(dst + (size_t)h * 8) = v;
    }
  }
}

// ---- async 16B global -> LDS
__device__ __forceinline__ void g2l16(const void* g, void* l) {
  __builtin_amdgcn_global_load_lds(
      (const __attribute__((address_space(1))) void*)g,
      (__attribute__((address_space(3))) void*)l, 16, 0, 0);
}

// ---- main fused kernel: one WG (256 thr, 4 waves) per (g,p) pair ----
// m201-style phase discipline on the R15 frame (BK=32, triple buffer, stage
// lead 2).  Each kc is a phase: {READ6 (ds_read before barrier) -> STAGE ->
// s_barrier -> lgkmcnt(0) -> 9 MFMA (setprio) -> s_barrier}.  The barrier-pair
// per phase (a) absorbs ds_read latency in barrier slack, (b) isolates the
// MFMA cluster so the LDS and matrix pipes alternate cleanly across the two
// antiphase blocks, (c) guarantees all waves' reads are complete before any
// wave's next STAGE overwrites a retired buffer (closes the triple-buffer
// race).  vmcnt(6) once per kt keeps stage(kt+2) in flight across barriers.
__global__ __launch_bounds__(256, 2) void qaconv_main(
    const _Float16* __restrict__ galT4, const _Float16* __restrict__ probT4,
    const float* __restrict__ bn_w, const float* __restrict__ bn_b,
    const float* __restrict__ bn_m, const float* __restrict__ bn_v,
    const float* __restrict__ fc_w, const float* __restrict__ fc_b,
    const float* __restrict__ lbn_w, const float* __restrict__ lbn_b,
    const float* __restrict__ lbn_m, const float* __restrict__ lbn_v,
    float* __restrict__ out) {
  // K-loop: 3 buffers x [A 12KB | B 12KB] = 73728 B; epilogue overlays
  // rowbuf[192][66] f32 (50688 B) on the same storage.
  __shared__ __align__(16) char shmem[73728];
  __shared__ float colp[2][HW];
  __shared__ float wsum[4];
  float(*rowbuf)[66] = (float(*)[66])shmem;

  const int bid = blockIdx.x;
  const int g = bid >> 6, p = bid & 63;

  const int t = threadIdx.x;
  const int lane = t & 63, wid = t >> 6;
  const int wr = wid & 1;   // probe-row half (y block of 96)
  const int wc = wid >> 1;  // gal-col half (x block of 96)
  const int l31 = lane & 31, hi = lane >> 5;

  // staging sources (per-lane): one BK=32 tile = 12KB linear per operand.
  const _Float16* pAl = probT4 + (size_t)p * 98304 + wid * 512 + lane * 8;
  const _Float16* pBl = galT4 + (size_t)g * 98304 + wid * 512 + lane * 8;
  const int sdst = wid * 1024;  // wave-uniform LDS dest base (+ lane*16 by HW)

  char* const b0 = shmem;
  char* const b1 = shmem + 24576;
  char* const b2 = shmem + 49152;

  floatx16 acc[3][3];
#pragma unroll
  for (int ii = 0; ii < 3; ++ii)
#pragma unroll
    for (int jj = 0; jj < 3; ++jj) acc[ii][jj] = (floatx16)0.f;

  half8 raf[3], rbf[3];

#define STAGE(kt_, base_)                                            \
  {                                                                  \
    char* db_ = (base_) + sdst;                                      \
    const _Float16* sa_ = pAl + (size_t)(kt_)*6144;                  \
    const _Float16* sb_ = pBl + (size_t)(kt_)*6144;                  \
    g2l16(sa_, db_);                                                 \
    g2l16(sa_ + 2048, db_ + 4096);                                   \
    g2l16(sa_ + 4096, db_ + 8192);                                   \
    g2l16(sb_, db_ + 12288);                                         \
    g2l16(sb_ + 2048, db_ + 16384);                                  \
    g2l16(sb_ + 4096, db_ + 20480);                                  \
  }

#define READ6(base_, kc_)                                            \
  {                                                                  \
    const char* bA_ = (base_) + (kc_)*6144;                          \
    const char* bB_ = (base_) + 12288 + (kc_)*6144;                  \
    raf[0] = *(const half8*)(bA_ + (wr * 3 + 0) * 1024 + lane * 16); \
    raf[1] = *(const half8*)(bA_ + (wr * 3 + 1) * 1024 + lane * 16); \
    raf[2] = *(const half8*)(bA_ + (wr * 3 + 2) * 1024 + lane * 16); \
    rbf[0] = *(const half8*)(bB_ + (wc * 3 + 0) * 1024 + lane * 16); \
    rbf[1] = *(const half8*)(bB_ + (wc * 3 + 1) * 1024 + lane * 16); \
    rbf[2] = *(const half8*)(bB_ + (wc * 3 + 2) * 1024 + lane * 16); \
  }

#define MFMA9()                                                                  \
  {                                                                              \
    __builtin_amdgcn_s_setprio(1);                                               \
    _Pragma("unroll") for (int ii = 0; ii < 3; ++ii)                             \
        _Pragma("unroll") for (int jj = 0; jj < 3; ++jj)                         \
            acc[ii][jj] = __builtin_amdgcn_mfma_f32_32x32x16_f16(raf[ii], rbf[jj],\
                                                                 acc[ii][jj], 0, 0, 0); \
    __builtin_amdgcn_s_setprio(0);                                               \
  }

  // SLOT: one kt = two phases.  vmW_ is the phase-1 vmcnt immediate (token).
#define SLOT(kt_, rdb_, stb_, doStage_, vmW_)                        \
  {                                                                  \
    /* phase 0 */                                                    \
    READ6(rdb_, 0)                                                   \
    if (doStage_) STAGE((kt_) + 2, stb_)                             \
    __builtin_amdgcn_sched_barrier(0);                               \
    __builtin_amdgcn_s_barrier();                                    \
    asm volatile("s_waitcnt lgkmcnt(0)" ::: "memory");               \
    __builtin_amdgcn_sched_barrier(0);                               \
    MFMA9()                                                          \
    __builtin_amdgcn_s_barrier();                                    \
    /* phase 1 */                                                    \
    READ6(rdb_, 1)                                                   \
    __builtin_amdgcn_sched_barrier(0);                               \
    asm volatile("s_waitcnt vmcnt(" #vmW_ ")" ::: "memory");         \
    __builtin_amdgcn_s_barrier();                                    \
    asm volatile("s_waitcnt lgkmcnt(0)" ::: "memory");               \
    __builtin_amdgcn_sched_barrier(0);                               \
    MFMA9()                                                          \
    __builtin_amdgcn_s_barrier();                                    \
  }

  // prologue: stage tiles 0,1; ensure stage(0) complete before kt0 reads
  STAGE(0, b0)
  STAGE(1, b1)
  asm volatile("s_waitcnt vmcnt(6)" ::: "memory");
  __builtin_amdgcn_s_barrier();

#pragma unroll 1
  for (int m = 0; m < 4; ++m) {  // kt = 0..11
    SLOT(3 * m + 0, b0, b2, true, 6)
    SLOT(3 * m + 1, b1, b0, true, 6)
    SLOT(3 * m + 2, b2, b1, true, 6)
  }
  SLOT(12, b0, b2, true, 6)
  SLOT(13, b1, b0, true, 6)   // stage(15) -> b0
  SLOT(14, b2, b1, false, 0)  // no stage(16); vmcnt(0) drains stage(15)
  SLOT(15, b0, b1, false, 0)
#undef STAGE
#undef READ6
#undef MFMA9
#undef SLOT

  // ---- epilogue: dual-axis max ----
  // C/D map: col X = wc*96 + fb*32 + l31, row Y = wr*96 + fa*32 + (e&3)+8*(e>>2)+4*hi
#pragma unroll
  for (int fb = 0; fb < 3; ++fb) {
    float v = -3.4e38f;
#pragma unroll
    for (int fa = 0; fa < 3; ++fa)
#pragma unroll
      for (int e = 0; e < 16; ++e) v = fmaxf(v, acc[fa][fb][e]);
    v = fmaxf(v, __shfl_xor(v, 32));
    if (lane < 32) colp[wr][wc * 96 + fb * 32 + lane] = v;
  }
  __syncthreads();  // all waves done with LDS tiles -> safe to overlay rowbuf
  // rowmax partials -> rowbuf (overlays tile storage)
#pragma unroll
  for (int fa = 0; fa < 3; ++fa)
#pragma unroll
    for (int e = 0; e < 16; ++e) {
      float rv = acc[fa][0][e];
      rv = fmaxf(rv, acc[fa][1][e]);
      rv = fmaxf(rv, acc[fa][2][e]);
      const int Y = wr * 96 + fa * 32 + (e & 3) + 8 * (e >> 2) + 4 * hi;
      rowbuf[Y][wc * 32 + l31] = rv;
    }
  __syncthreads();

  // ---- fused BN -> fc dot -> logit BN -> sigmoid ----
  float partial = 0.f;
  if (t < HW) {
    const float* rb = rowbuf[t];
    float rmax = -3.4e38f;
#pragma unroll
    for (int j = 0; j < 16; ++j) {
      const floatx4 v = *(const floatx4*)&rb[j * 4];
      rmax = fmaxf(rmax, fmaxf(fmaxf(v[0], v[1]), fmaxf(v[2], v[3])));
    }
    const float cmax = fmaxf(colp[0][t], colp[1][t]);
    const float scale = bn_w[0] / sqrtf(bn_v[0] + EPSV);
    const float bm = bn_m[0], bb = bn_b[0];
    partial = ((cmax - bm) * scale + bb) * fc_w[t] +
              ((rmax - bm) * scale + bb) * fc_w[HW + t];
  }
#pragma unroll
  for (int off = 1; off < 64; off <<= 1) partial += __shfl_xor(partial, off);
  if (lane == 0) wsum[wid] = partial;
  __syncthreads();
  if (t == 0) {
    const float sum = fc_b[0] + wsum[0] + wsum[1] + wsum[2] + wsum[3];
    const float logit = (sum - lbn_m[0]) * (lbn_w[0] / sqrtf(lbn_v[0] + EPSV)) + lbn_b[0];
    out[bid] = 1.f / (1.f + expf(-logit * 0.1f));
  }
}

// ---------------- naive f32 fallback (only if ws too small) ----------------
__global__ __launch_bounds__(256) void qaconv_naive(
    const float* __restrict__ gal, const float* __restrict__ prob,
    const float* __restrict__ bn_w, const float* __restrict__ bn_b,
    const float* __restrict__ bn_m, const float* __restrict__ bn_v,
    const float* __restrict__ fc_w, const float* __restrict__ fc_b,
    const float* __restrict__ lbn_w, const float* __restrict__ lbn_b,
    const float* __restrict__ lbn_m, const float* __restrict__ lbn_v,
    float* __restrict__ out) {
  __shared__ float prow[ND];
  __shared__ float rowmaxs[HW];
  __shared__ float colmaxs[HW];
  __shared__ float red[4];
  const int bid = blockIdx.x;
  const int g = bid >> 6, p = bid & 63;
  const int t = threadIdx.x, lane = t & 63, wid = t >> 6;
  const float* gp = gal + (size_t)g * ND * HW;
  const float* pp = prob + (size_t)p * ND * HW;
  float colmax = -3.4e38f;
  for (int y = 0; y < HW; ++y) {
    for (int k = t; k < ND; k += 256) prow[k] = pp[(size_t)k * HW + y];
    __syncthreads();
    float sv = -3.4e38f;
    if (t < HW) {
      sv = 0.f;
      for (int k = 0; k < ND; ++k) sv = fmaf(prow[k], gp[(size_t)k * HW + t], sv);
      colmax = fmaxf(colmax, sv);
    }
    float m = sv;
#pragma unroll
    for (int off = 1; off < 64; off <<= 1) m = fmaxf(m, __shfl_xor(m, off));
    if (lane == 0) red[wid] = m;
    __syncthreads();
    if (t == 0) rowmaxs[y] = fmaxf(fmaxf(red[0], red[1]), fmaxf(red[2], red[3]));
    __syncthreads();
  }
  if (t < HW) colmaxs[t] = colmax;
  __syncthreads();
  float partial = 0.f;
  for (int j = t; j < 2 * HW; j += 256) {
    const float v = (j < HW) ? colmaxs[j] : rowmaxs[j - HW];
    const float sc = (v - bn_m[0]) * (bn_w[0] / sqrtf(bn_v[0] + EPSV)) + bn_b[0];
    partial += sc * fc_w[j];
  }
#pragma unroll
  for (int off = 1; off < 64; off <<= 1) partial += __shfl_xor(partial, off);
  if (lane == 0) red[wid] = partial;
  __syncthreads();
  if (t == 0) {
    const float sum = fc_b[0] + red[0] + red[1] + red[2] + red[3];
    const float logit = (sum - lbn_m[0]) * (lbn_w[0] / sqrtf(lbn_v[0] + EPSV)) + lbn_b[0];
    out[bid] = 1.f / (1.f + expf(-logit * 0.1f));
  }
}

extern "C" void kernel_launch(void* const* d_in, const int* in_sizes, int n_in,
                              void* d_out, int out_size, void* d_ws, size_t ws_size,
                              hipStream_t stream) {
  const float* gal = (const float*)d_in[0];
  const float* prob = (const float*)d_in[1];
  const float* bn_w = (const float*)d_in[2];
  const float* bn_b = (const float*)d_in[3];
  const float* bn_m = (const float*)d_in[4];
  const float* bn_v = (const float*)d_in[5];
  const float* fc_w = (const float*)d_in[6];
  const float* fc_b = (const float*)d_in[7];
  const float* lbn_w = (const float*)d_in[8];
  const float* lbn_b = (const float*)d_in[9];
  const float* lbn_m = (const float*)d_in[10];
  const float* lbn_v = (const float*)d_in[11];
  float* out = (float*)d_out;

  const size_t probT4_elems = (size_t)NP * 98304;  // 6.29M halves
  const size_t galT4_elems = (size_t)NG * 98304;   // 3.15M halves
  const size_t ws_needed = (probT4_elems + galT4_elems) * sizeof(_Float16);
  if (ws_size >= ws_needed) {
    _Float16* probT4 = (_Float16*)d_ws;
    _Float16* galT4 = probT4 + probT4_elems;
    prep_frag<<<dim3(NP + NG, KS), dim3(256), 0, stream>>>(gal, prob, galT4, probT4);
    qaconv_main<<<dim3(NG * NP), dim3(256), 0, stream>>>(
        galT4, probT4, bn_w, bn_b, bn_m, bn_v, fc_w, fc_b, lbn_w, lbn_b, lbn_m, lbn_v, out);
  } else {
    qaconv_naive<<<dim3(NG * NP), dim3(256), 0, stream>>>(
        gal, prob, bn_w, bn_b, bn_m, bn_v, fc_w, fc_b, lbn_w, lbn_b, lbn_m, lbn_v, out);
  }
}